// Round 21
// baseline (182.312 us; speedup 1.0000x reference)
//
#include <hip/hip_runtime.h>

#define B_   32
#define NL_  64
#define NP_  4096
#define DIM_ 192
#define H_   6
#define HD_  32
#define PC_  128
#define NCH_ (NP_/PC_)   // 32 chunks
#define CPB_ 4           // chunks per k_attn block
#define NSC_ (NCH_/CPB_) // 8 super-chunks

typedef unsigned short u16;
typedef __attribute__((ext_vector_type(8))) short bf16x8;
typedef __attribute__((ext_vector_type(4))) short bf16x4;
typedef __attribute__((ext_vector_type(4))) float f32x4;

#define MFMA16(a,b,c) __builtin_amdgcn_mfma_f32_16x16x32_bf16(a,b,c,0,0,0)

__device__ __forceinline__ float bf2f(u16 s){ return __builtin_bit_cast(float,(unsigned)s<<16); }
__device__ __forceinline__ u16 f2bf(float f){
  unsigned u = __builtin_bit_cast(unsigned,f);
  return (u16)((u + 0x7FFFu + ((u>>16)&1u))>>16);
}

// ---------------- K0: transpose+convert weights W[k][n] (f32) -> Wt[n][k] (bf16) ----------------
__global__ void k0_transpose(const float* __restrict__ W0, const float* __restrict__ W1,
                             const float* __restrict__ W2, const float* __restrict__ W3,
                             u16* __restrict__ T0, u16* __restrict__ T1,
                             u16* __restrict__ T2, u16* __restrict__ T3){
  int m = blockIdx.x >> 4, sub = blockIdx.x & 15;
  const float* src; u16* dst; int R, C;
  if      (m==0){src=W0;dst=T0;R=192;C=384;}
  else if (m==1){src=W1;dst=T1;R=192;C=384;}
  else if (m==2){src=W2;dst=T2;R=192;C=192;}
  else          {src=W3;dst=T3;R=192;C=192;}
  int total = R*C;
  for (int o = sub*256 + threadIdx.x; o < total; o += 16*256){
    int c = o / R, r = o - c*R;        // dst-linear: o == c*R + r
    dst[o] = f2bf(src[r*C + c]);
  }
}

// ---------------- K1: rv = X @ W_rv  (X f32, Wt bf16 [384][192]) ----------------
// r20 structure + STORE-AFTER-BARRIER: barrier no longer drains fresh stores;
// stores of iter c overlap iter c+1's stage+MFMA.
__global__ __launch_bounds__(512,2) void k_rv(const float* __restrict__ X,
    const u16* __restrict__ Wt, u16* __restrict__ R, u16* __restrict__ V,
    int Nseq, int nshift){
  __shared__ u16 Bs[2][64*192];
  const int t = threadIdx.x;
  const int m0 = blockIdx.x*256;
  const int lane = t & 63, w = t >> 6, g = lane >> 4, ln = lane & 15;
  const int srB = t >> 3, bq = t & 7;          // Bs staging: 64 rows x 24-col eighths
  const f32x4 ZF = {0.f,0.f,0.f,0.f};

  // A fragments in regs: wave's 32 rows (i=0,1), K=192 in 6 slices
  bf16x8 af[2][6];
  #pragma unroll
  for (int i=0;i<2;i++)
    #pragma unroll
    for (int kk=0;kk<6;kk++){
      const float* s = &X[(size_t)(m0 + w*32 + i*16 + ln)*192 + kk*32 + g*8];
      float4 x0 = *(const float4*)s;
      float4 x1 = *(const float4*)(s+4);
      bf16x8 v;
      v[0]=(short)f2bf(x0.x); v[1]=(short)f2bf(x0.y); v[2]=(short)f2bf(x0.z); v[3]=(short)f2bf(x0.w);
      v[4]=(short)f2bf(x1.x); v[5]=(short)f2bf(x1.y); v[6]=(short)f2bf(x1.z); v[7]=(short)f2bf(x1.w);
      af[i][kk] = v;
    }

  // prologue: stage Bs[0] (n0=0) swizzled, prefetch n0=64
  bf16x8 breg[3];
  #pragma unroll
  for (int it=0; it<3; it++)
    breg[it] = *(const bf16x8*)&Wt[(size_t)srB*192 + bq*24 + it*8];
  #pragma unroll
  for (int it=0; it<3; it++){
    int sl = (3*bq + it) ^ (srB & 7);
    *(bf16x8*)&Bs[0][srB*192 + sl*8] = breg[it];
  }
  #pragma unroll
  for (int it=0; it<3; it++)
    breg[it] = *(const bf16x8*)&Wt[(size_t)(64 + srB)*192 + bq*24 + it*8];
  __syncthreads();   // Bs[0] ready

  for (int c = 0; c < 6; ++c){
    // write next buffer (swizzled); prefetch the one after
    if (c < 5){
      u16* bn = &Bs[(c+1)&1][0];
      #pragma unroll
      for (int it=0; it<3; it++){
        int sl = (3*bq + it) ^ (srB & 7);
        *(bf16x8*)&bn[srB*192 + sl*8] = breg[it];
      }
      if (c < 4){
        #pragma unroll
        for (int it=0; it<3; it++)
          breg[it] = *(const bf16x8*)&Wt[(size_t)((c+2)*64 + srB)*192 + bq*24 + it*8];
      }
    }
    const u16* bc = &Bs[c&1][0];
    f32x4 accT[4][2];   // [n-frag j][m-frag i] : D = C^T
    #pragma unroll
    for(int j=0;j<4;j++){ accT[j][0]=ZF; accT[j][1]=ZF; }
    #pragma unroll
    for (int kk=0; kk<6; kk++)
      #pragma unroll
      for (int j=0; j<4; j++){
        bf16x8 bv = *(const bf16x8*)&bc[(j*16 + ln)*192 + (((4*kk + g) ^ (ln & 7)) << 3)];
        accT[j][0] = MFMA16(bv, af[0][kk], accT[j][0]);
        accT[j][1] = MFMA16(bv, af[1][kk], accT[j][1]);
      }
    __syncthreads();   // reads of Bs[c&1] done; (c+1)&1 writes visible; NO fresh stores to drain

    // stores AFTER barrier: overlap next iter's stage+compute
    #pragma unroll
    for(int j=0;j<4;j++){
      int nb = c*64 + j*16 + g*4;          // 16-aligned frag: never crosses d/RV boundary
      u16* dst; int cc;
      if (nb < 192){ dst = R; cc = nb; } else { dst = V; cc = nb - 192; }
      int h = cc >> 5, d0 = cc & 31;
      #pragma unroll
      for(int i=0;i<2;i++){
        int m = m0 + w*32 + i*16 + ln;
        int b = m >> nshift, sidx = m & (Nseq-1);
        bf16x4 pk;
        #pragma unroll
        for(int r=0;r<4;r++) pk[r] = (short)f2bf(accT[j][i][r]);
        *(bf16x4*)&dst[((((size_t)b*H_ + h)*(size_t)Nseq + sidx) << 5) + d0] = pk;
      }
    }
  }
}

// ---------------- K2: per-head, 4-chunk k_attn; phase B hoisted (EN is wave-private) ----------------
__global__ __launch_bounds__(256) void k_attn(
    const u16* __restrict__ r_lat_g, const u16* __restrict__ v_lat_g,
    const u16* __restrict__ r_pat_g, const u16* __restrict__ v_pat_g,
    u16* __restrict__ Opat,            // [B][4096][192] bf16 (pre-projection)
    float* __restrict__ numT_ws,       // [B*H][NSC][64*32]
    float* __restrict__ rowsum_ws){    // [B*H][NSC][64]
  const float SCALE = 0.17677669529663687f;
  const int sc = blockIdx.x, h = blockIdx.y, b = blockIdx.z;
  const int bh = b*H_ + h;
  const int t = threadIdx.x, lane = t&63, w = t>>6, g = lane>>4, ln = lane&15;
  __shared__ u16 RL [64*40];    // r_lat [l][d]
  __shared__ u16 VLT[32*72];    // v_lat^T [d][l]
  __shared__ u16 EN [128*72];   // normalized e [p][l] — WAVE-PRIVATE rows
  __shared__ u16 ET [64*136];   // raw e^T [l][p]
  __shared__ float RS[4*64];
  __shared__ u16 POOL[128*40];  // RP [p][d] pad40 / VPT [d][p] pad136 overlay
  u16* RP  = POOL;
  u16* VPT = POOL;
  const f32x4 ZF = {0.f,0.f,0.f,0.f};

  // stage RL, VLT once per block
  const size_t latbase = (size_t)bh * (NL_*HD_);
  { int row = t>>2, col = (t&3)*8;
    *(bf16x8*)&RL[row*40+col] = *(const bf16x8*)&r_lat_g[latbase + row*32 + col]; }
  { int l = t>>2, dd = (t&3)*8;
    bf16x8 v = *(const bf16x8*)&v_lat_g[latbase + l*32 + dd];
    #pragma unroll
    for(int jj=0;jj<8;jj++) VLT[(dd+jj)*72 + l] = (u16)v[jj]; }

  const int p0 = t>>2, dd0 = (t&3)*8;
  const size_t pb0 = ((size_t)bh*NP_ + (size_t)sc*(CPB_*PC_))*HD_;
  // prologue: load chunk 0 r/v into regs
  bf16x8 rcur0 = *(const bf16x8*)&r_pat_g[pb0 + (size_t)p0*32 + dd0];
  bf16x8 rcur1 = *(const bf16x8*)&r_pat_g[pb0 + (size_t)(64+p0)*32 + dd0];
  bf16x8 vcur0 = *(const bf16x8*)&v_pat_g[pb0 + (size_t)p0*32 + dd0];
  bf16x8 vcur1 = *(const bf16x8*)&v_pat_g[pb0 + (size_t)(64+p0)*32 + dd0];

  f32x4 nmT[2]; nmT[0]=ZF; nmT[1]=ZF;     // row-softmax numerator accum, TRANSPOSED [d][l]
  float rs[4] = {0.f,0.f,0.f,0.f};        // rowsum accum

  for (int c = 0; c < CPB_; ++c){
    // write RP (after prev b4, so VPT reads are done)
    *(bf16x8*)&RP[p0*40 + dd0]      = rcur0;
    *(bf16x8*)&RP[(64+p0)*40 + dd0] = rcur1;
    __syncthreads();   // b1: RP ready (iter0: RL/VLT also)

    // ---- phase A: scores s[p][l], wave's 32 p, all 64 l ----
    f32x4 sf[2][4];
    { bf16x8 a0 = *(const bf16x8*)&RP[(w*32      + ln)*40 + g*8];
      bf16x8 a1 = *(const bf16x8*)&RP[(w*32 + 16 + ln)*40 + g*8];
      #pragma unroll
      for(int j=0;j<4;j++){
        bf16x8 bl = *(const bf16x8*)&RL[(j*16 + ln)*40 + g*8];
        sf[0][j] = MFMA16(a0, bl, ZF);
        sf[1][j] = MFMA16(a1, bl, ZF);
      } }

    // issue next chunk's loads early (hide under B/C phases)
    bf16x8 rnxt0, rnxt1, vnxt0, vnxt1;
    const bool more = (c+1 < CPB_);
    if (more){
      const size_t pbn = pb0 + (size_t)(c+1)*(PC_*HD_);
      rnxt0 = *(const bf16x8*)&r_pat_g[pbn + (size_t)p0*32 + dd0];
      rnxt1 = *(const bf16x8*)&r_pat_g[pbn + (size_t)(64+p0)*32 + dd0];
      vnxt0 = *(const bf16x8*)&v_pat_g[pbn + (size_t)p0*32 + dd0];
      vnxt1 = *(const bf16x8*)&v_pat_g[pbn + (size_t)(64+p0)*32 + dd0];
    }

    float e[2][4][4], rcs[2][4];
    #pragma unroll
    for(int i=0;i<2;i++)
      #pragma unroll
      for(int r=0;r<4;r++){
        float cs = 0.f;
        #pragma unroll
        for(int j=0;j<4;j++){
          float ev = __expf(sf[i][j][r] * SCALE);
          e[i][j][r] = ev; cs += ev; rs[j] += ev;
        }
        cs += __shfl_xor(cs,1); cs += __shfl_xor(cs,2);
        cs += __shfl_xor(cs,4); cs += __shfl_xor(cs,8);
        rcs[i][r] = 1.0f / cs;
      }
    #pragma unroll
    for(int i=0;i<2;i++)
      #pragma unroll
      for(int j=0;j<4;j++){
        #pragma unroll
        for(int r=0;r<4;r++)
          EN[(w*32 + i*16 + g*4 + r)*72 + j*16 + ln] = f2bf(e[i][j][r]*rcs[i][r]);
        bf16x4 pk;
        #pragma unroll
        for(int r=0;r<4;r++) pk[r] = (short)f2bf(e[i][j][r]);
        *(bf16x4*)&ET[(j*16+ln)*136 + w*32 + i*16 + g*4] = pk;
      }

    // ---- phase B (HOISTED, pre-b2): EN rows are wave-private; VLT block-static ----
    f32x4 opT[2][2];   // [jd d-frag][i p-frag]
    #pragma unroll
    for(int jd=0;jd<2;jd++){ opT[jd][0]=ZF; opT[jd][1]=ZF; }
    #pragma unroll
    for(int ks=0; ks<2; ks++){
      bf16x8 bv[2];
      #pragma unroll
      for(int jd=0;jd<2;jd++) bv[jd] = *(const bf16x8*)&VLT[(jd*16+ln)*72 + ks*32 + g*8];
      #pragma unroll
      for(int i=0;i<2;i++){
        bf16x8 afen = *(const bf16x8*)&EN[(w*32 + i*16 + ln)*72 + ks*32 + g*8];
        #pragma unroll
        for(int jd=0;jd<2;jd++) opT[jd][i] = MFMA16(bv[jd], afen, opT[jd][i]);
      }
    }
    const size_t obase = ((size_t)b*NP_ + (size_t)(sc*CPB_ + c)*PC_)*DIM_ + h*32;
    #pragma unroll
    for(int jd=0;jd<2;jd++)
      #pragma unroll
      for(int i=0;i<2;i++){
        int p = w*32 + i*16 + ln, d0 = jd*16 + g*4;
        bf16x4 pk;
        #pragma unroll
        for(int r=0;r<4;r++) pk[r] = (short)f2bf(opT[jd][i][r]);
        *(bf16x4*)&Opat[obase + (size_t)p*DIM_ + d0] = pk;
      }
    __syncthreads();   // b2: ET visible; all RP reads done -> POOL free

    // stage VPT [d][p] from vcur
    #pragma unroll
    for(int jj=0;jj<8;jj++){
      VPT[(dd0+jj)*136 + p0]      = (u16)vcur0[jj];
      VPT[(dd0+jj)*136 + 64 + p0] = (u16)vcur1[jj];
    }
    __syncthreads();   // b3: VPT writes complete

    // ---- phase C: row-softmax numerator, SWAPPED (D[d][l]), accumulate ----
    #pragma unroll
    for(int ks=0; ks<4; ks++){
      bf16x8 afet = *(const bf16x8*)&ET[(w*16+ln)*136 + ks*32 + g*8];
      #pragma unroll
      for(int dj=0;dj<2;dj++){
        bf16x8 bv = *(const bf16x8*)&VPT[(dj*16+ln)*136 + ks*32 + g*8];
        nmT[dj] = MFMA16(bv, afet, nmT[dj]);
      }
    }
    __syncthreads();   // b4: ET/VPT reads done -> next chunk may overwrite

    if (more){ rcur0=rnxt0; rcur1=rnxt1; vcur0=vnxt0; vcur1=vnxt1; }
  }

  // ---- epilogue: rowsum + numT (once per block) ----
  #pragma unroll
  for(int j=0;j<4;j++){
    float vs = rs[j];
    vs += __shfl_xor(vs,16); vs += __shfl_xor(vs,32);
    if (g == 0) RS[w*64 + j*16 + ln] = vs;
  }
  __syncthreads();
  if (t < 64)
    rowsum_ws[((size_t)bh*NSC_ + sc)*64 + t] = RS[t] + RS[64+t] + RS[128+t] + RS[192+t];
  float* dstN = numT_ws + ((size_t)bh*NSC_ + sc)*2048;
  #pragma unroll
  for(int dj=0;dj<2;dj++){
    int l = w*16 + ln, d0 = dj*16 + g*4;
    *(f32x4*)&dstN[l*32 + d0] = nmT[dj];
  }
}

// ---------------- K3a: reduce super-chunk partials -> attn_lat [B][64][192] bf16 ----------------
__global__ __launch_bounds__(256) void k_lat_reduce(const float* __restrict__ numT_ws,
    const float* __restrict__ rowsum_ws, u16* __restrict__ attn_lat){
  int bh = blockIdx.x, b = bh / H_, h = bh - b*H_;
  __shared__ float RSs[64];
  int t = threadIdx.x;
  if (t < 64){
    float s = 0.f;
    for(int c=0;c<NSC_;c++) s += rowsum_ws[((size_t)bh*NSC_ + c)*64 + t];
    RSs[t] = 1.0f / s;
  }
  __syncthreads();
  for(int idx = t; idx < 2048; idx += 256){
    int l = idx >> 5, dd = idx & 31;
    float s = 0.f;
    for(int c=0;c<NSC_;c++) s += numT_ws[((size_t)bh*NSC_ + c)*2048 + idx];
    attn_lat[((size_t)b*NL_ + l)*DIM_ + h*32 + dd] = f2bf(s * RSs[l]);
  }
}

// ---------------- K3b: out_lat = attn_lat @ W_proj_lat + b (f32 out) ----------------
__global__ __launch_bounds__(256) void k_proj_lat(const u16* __restrict__ A,
    const u16* __restrict__ Wt, const float* __restrict__ bias, float* __restrict__ out){
  int b = blockIdx.x;
  __shared__ u16 As[64*40];
  __shared__ u16 Bs[192*40];
  int t = threadIdx.x, lane = t&63, w = t>>6, g = lane>>4, ln = lane&15;
  const f32x4 ZF = {0.f,0.f,0.f,0.f};
  f32x4 acc[4][3];
  #pragma unroll
  for(int i=0;i<4;i++)
    #pragma unroll
    for(int j=0;j<3;j++) acc[i][j]=ZF;
  for(int k0=0;k0<192;k0+=32){
    bf16x8 av; bf16x8 bv[3];
    { int row = t>>2, col=(t&3)*8;
      av = *(const bf16x8*)&A[((size_t)b*NL_ + row)*DIM_ + k0 + col]; }
    #pragma unroll
    for(int it=0;it<3;it++){
      int e = it*2048 + t*8, row = e>>5, col = (t&3)*8;
      bv[it] = *(const bf16x8*)&Wt[(size_t)row*192 + k0 + col];
    }
    if (k0) __syncthreads();
    { int row = t>>2, col=(t&3)*8; *(bf16x8*)&As[row*40+col] = av; }
    #pragma unroll
    for(int it=0;it<3;it++){
      int e = it*2048 + t*8, row = e>>5, col = (t&3)*8;
      *(bf16x8*)&Bs[row*40+col] = bv[it];
    }
    __syncthreads();
    bf16x8 bw[3];
    #pragma unroll
    for(int jf=0;jf<3;jf++) bw[jf] = *(const bf16x8*)&Bs[(w*48 + jf*16 + ln)*40 + g*8];
    #pragma unroll
    for(int lf=0;lf<4;lf++){
      bf16x8 af = *(const bf16x8*)&As[(lf*16 + ln)*40 + g*8];
      #pragma unroll
      for(int jf=0;jf<3;jf++) acc[lf][jf] = MFMA16(af, bw[jf], acc[lf][jf]);
    }
  }
  #pragma unroll
  for(int lf=0;lf<4;lf++)
    #pragma unroll
    for(int jf=0;jf<3;jf++){
      int j = w*48 + jf*16 + ln;
      float bs = bias[j];
      #pragma unroll
      for(int r=0;r<4;r++){
        int l = lf*16 + g*4 + r;
        out[((size_t)b*NL_ + l)*DIM_ + j] = acc[lf][jf][r] + bs;
      }
    }
}

// ---------------- K4: out_pat = Opat @ W_proj_pat + b (f32 out) ----------------
// r20 structure + store-after-barrier.
__global__ __launch_bounds__(512,2) void k_proj_pat(const u16* __restrict__ X,
    const u16* __restrict__ Wt, const float* __restrict__ bias, float* __restrict__ out){
  __shared__ u16 Bs[2][64*192];
  const int t = threadIdx.x;
  const int m0 = blockIdx.x*256;
  const int lane = t & 63, w = t >> 6, g = lane >> 4, ln = lane & 15;
  const int srB = t >> 3, bq = t & 7;
  const f32x4 ZF = {0.f,0.f,0.f,0.f};

  // A fragments in regs (bf16 input, direct loads)
  bf16x8 af[2][6];
  #pragma unroll
  for (int i=0;i<2;i++)
    #pragma unroll
    for (int kk=0;kk<6;kk++)
      af[i][kk] = *(const bf16x8*)&X[(size_t)(m0 + w*32 + i*16 + ln)*192 + kk*32 + g*8];

  bf16x8 breg[3];
  #pragma unroll
  for (int it=0; it<3; it++)
    breg[it] = *(const bf16x8*)&Wt[(size_t)srB*192 + bq*24 + it*8];
  #pragma unroll
  for (int it=0; it<3; it++){
    int sl = (3*bq + it) ^ (srB & 7);
    *(bf16x8*)&Bs[0][srB*192 + sl*8] = breg[it];
  }
  #pragma unroll
  for (int it=0; it<3; it++)
    breg[it] = *(const bf16x8*)&Wt[(size_t)(64 + srB)*192 + bq*24 + it*8];
  __syncthreads();

  for (int c = 0; c < 3; ++c){
    if (c < 2){
      u16* bn = &Bs[(c+1)&1][0];
      #pragma unroll
      for (int it=0; it<3; it++){
        int sl = (3*bq + it) ^ (srB & 7);
        *(bf16x8*)&bn[srB*192 + sl*8] = breg[it];
      }
      if (c < 1){
        #pragma unroll
        for (int it=0; it<3; it++)
          breg[it] = *(const bf16x8*)&Wt[(size_t)((c+2)*64 + srB)*192 + bq*24 + it*8];
      }
    }
    const u16* bc = &Bs[c&1][0];
    f32x4 accT[4][2];
    #pragma unroll
    for(int j=0;j<4;j++){ accT[j][0]=ZF; accT[j][1]=ZF; }
    #pragma unroll
    for (int kk=0; kk<6; kk++)
      #pragma unroll
      for (int j=0; j<4; j++){
        bf16x8 bv = *(const bf16x8*)&bc[(j*16 + ln)*192 + (((4*kk + g) ^ (ln & 7)) << 3)];
        accT[j][0] = MFMA16(bv, af[0][kk], accT[j][0]);
        accT[j][1] = MFMA16(bv, af[1][kk], accT[j][1]);
      }
    __syncthreads();   // drains only prefetch loads; stores of prev iter already retired

    #pragma unroll
    for(int j=0;j<4;j++){
      int nb = c*64 + j*16 + g*4;
      float4 bs4 = *(const float4*)&bias[nb];
      #pragma unroll
      for(int i=0;i<2;i++){
        int m = m0 + w*32 + i*16 + ln;
        float4 o;
        o.x = accT[j][i][0] + bs4.x;
        o.y = accT[j][i][1] + bs4.y;
        o.z = accT[j][i][2] + bs4.z;
        o.w = accT[j][i][3] + bs4.w;
        *(float4*)&out[(size_t)m*192 + nb] = o;
      }
    }
  }
}

// ---------------- launch ----------------
extern "C" void kernel_launch(void* const* d_in, const int* in_sizes, int n_in,
                              void* d_out, int out_size, void* d_ws, size_t ws_size,
                              hipStream_t stream){
  const float* x_lat  = (const float*)d_in[0];
  const float* x_pat  = (const float*)d_in[1];
  const float* W_rv_l = (const float*)d_in[2];
  const float* W_rv_p = (const float*)d_in[3];
  const float* W_pj_l = (const float*)d_in[4];
  const float* b_pj_l = (const float*)d_in[5];
  const float* W_pj_p = (const float*)d_in[6];
  const float* b_pj_p = (const float*)d_in[7];
  float* out = (float*)d_out;

  char* ws = (char*)d_ws;
  size_t off = 0;
  auto alloc = [&](size_t bytes)->void*{ void* p = ws + off; off += (bytes + 255) & ~(size_t)255; return p; };
  u16* WtRL   = (u16*)alloc((size_t)384*192*2);
  u16* WtRP   = (u16*)alloc((size_t)384*192*2);
  u16* WtPL   = (u16*)alloc((size_t)192*192*2);
  u16* WtPP   = (u16*)alloc((size_t)192*192*2);
  u16* r_lat  = (u16*)alloc((size_t)B_*H_*NL_*HD_*2);
  u16* v_lat  = (u16*)alloc((size_t)B_*H_*NL_*HD_*2);
  u16* r_pat  = (u16*)alloc((size_t)B_*H_*NP_*HD_*2);
  u16* v_pat  = (u16*)alloc((size_t)B_*H_*NP_*HD_*2);
  u16* Opat   = (u16*)alloc((size_t)B_*NP_*DIM_*2);
  float* numT = (float*)alloc((size_t)B_*H_*NSC_*64*32*4);
  float* rsum = (float*)alloc((size_t)B_*H_*NSC_*64*4);
  u16* attn_l = (u16*)alloc((size_t)B_*NL_*DIM_*2);

  k0_transpose<<<64,256,0,stream>>>(W_rv_l, W_rv_p, W_pj_l, W_pj_p, WtRL, WtRP, WtPL, WtPP);
  k_rv<<<dim3((B_*NP_)/256),512,0,stream>>>(x_pat, WtRP, r_pat, v_pat, NP_, 12);
  k_rv<<<dim3((B_*NL_)/256),512,0,stream>>>(x_lat, WtRL, r_lat, v_lat, NL_, 6);
  k_attn<<<dim3(NSC_, H_, B_),256,0,stream>>>(r_lat, v_lat, r_pat, v_pat, Opat, numT, rsum);
  k_lat_reduce<<<B_*H_,256,0,stream>>>(numT, rsum, attn_l);
  k_proj_lat<<<B_,256,0,stream>>>(attn_l, WtPL, b_pj_l, out);
  k_proj_pat<<<dim3((B_*NP_)/256),512,0,stream>>>(Opat, WtPP, b_pj_p, out + (size_t)B_*NL_*DIM_);
}

// Round 22
// 171.995 us; speedup vs baseline: 1.0600x; 1.0600x over previous
//
#include <hip/hip_runtime.h>

#define B_   32
#define NL_  64
#define NP_  4096
#define DIM_ 192
#define H_   6
#define HD_  32
#define PC_  128
#define NCH_ (NP_/PC_)   // 32 chunks
#define CPB_ 4           // chunks per k_attn block
#define NSC_ (NCH_/CPB_) // 8 super-chunks

typedef unsigned short u16;
typedef __attribute__((ext_vector_type(8))) short bf16x8;
typedef __attribute__((ext_vector_type(4))) short bf16x4;
typedef __attribute__((ext_vector_type(4))) float f32x4;

#define MFMA16(a,b,c) __builtin_amdgcn_mfma_f32_16x16x32_bf16(a,b,c,0,0,0)

__device__ __forceinline__ float bf2f(u16 s){ return __builtin_bit_cast(float,(unsigned)s<<16); }
__device__ __forceinline__ u16 f2bf(float f){
  unsigned u = __builtin_bit_cast(unsigned,f);
  return (u16)((u + 0x7FFFu + ((u>>16)&1u))>>16);
}

// ---------------- K0: transpose+convert weights W[k][n] (f32) -> Wt[n][k] (bf16) ----------------
__global__ void k0_transpose(const float* __restrict__ W0, const float* __restrict__ W1,
                             const float* __restrict__ W2, const float* __restrict__ W3,
                             u16* __restrict__ T0, u16* __restrict__ T1,
                             u16* __restrict__ T2, u16* __restrict__ T3){
  int m = blockIdx.x >> 4, sub = blockIdx.x & 15;
  const float* src; u16* dst; int R, C;
  if      (m==0){src=W0;dst=T0;R=192;C=384;}
  else if (m==1){src=W1;dst=T1;R=192;C=384;}
  else if (m==2){src=W2;dst=T2;R=192;C=192;}
  else          {src=W3;dst=T3;R=192;C=192;}
  int total = R*C;
  for (int o = sub*256 + threadIdx.x; o < total; o += 16*256){
    int c = o / R, r = o - c*R;        // dst-linear: o == c*R + r
    dst[o] = f2bf(src[r*C + c]);
  }
}

// ---------------- K1: rv = X @ W_rv  (X f32, Wt bf16 [384][192]) ----------------
// r15 structure + T2 XOR-swizzled Bs: stride exact 192 (16B-aligned b128),
// 16B-slot index XOR'd with (row&7) on BOTH write and read (same involution).
__global__ __launch_bounds__(256,8) void k_rv(const float* __restrict__ X,
    const u16* __restrict__ Wt, u16* __restrict__ R, u16* __restrict__ V,
    int Nseq, int nshift){
  __shared__ u16 Bs[64*192];
  const int t = threadIdx.x;
  const int m0 = blockIdx.x*64;
  const int lane = t & 63, w = t >> 6, g = lane >> 4, ln = lane & 15;
  const int srB = t >> 2, bq = t & 3;      // Bs staging: 64 rows x 48-col quarters
  const f32x4 ZF = {0.f,0.f,0.f,0.f};

  // A fragments in regs: wave's 16 rows, K=192 in 6 slices (24 VGPR)
  bf16x8 af[6];
  #pragma unroll
  for (int kk=0;kk<6;kk++){
    const float* s = &X[(size_t)(m0 + w*16 + ln)*192 + kk*32 + g*8];
    float4 x0 = *(const float4*)s;
    float4 x1 = *(const float4*)(s+4);
    bf16x8 v;
    v[0]=(short)f2bf(x0.x); v[1]=(short)f2bf(x0.y); v[2]=(short)f2bf(x0.z); v[3]=(short)f2bf(x0.w);
    v[4]=(short)f2bf(x1.x); v[5]=(short)f2bf(x1.y); v[6]=(short)f2bf(x1.z); v[7]=(short)f2bf(x1.w);
    af[kk] = v;
  }

  // per-row base address
  const int mrow = m0 + w*16 + ln;
  const int b = mrow >> nshift, sidx = mrow & (Nseq-1);
  const size_t mbase = ((size_t)b*H_*(size_t)Nseq + (size_t)sidx) << 5;
  const size_t hstride = (size_t)Nseq << 5;

  for (int c = 0; c < 6; ++c){
    if (c) __syncthreads();              // prior iter's Bs reads done
    #pragma unroll
    for (int it=0; it<6; it++){
      int sl = (6*bq + it) ^ (srB & 7);  // swizzled 16B-slot
      *(bf16x8*)&Bs[srB*192 + sl*8] =
        *(const bf16x8*)&Wt[(size_t)(c*64 + srB)*192 + bq*48 + it*8];
    }
    __syncthreads();                     // Bs staged

    f32x4 acc[4];
    #pragma unroll
    for(int j=0;j<4;j++) acc[j]=ZF;
    #pragma unroll
    for (int kk=0; kk<6; kk++)
      #pragma unroll
      for (int j=0; j<4; j++){
        bf16x8 bv = *(const bf16x8*)&Bs[(j*16 + ln)*192 + (((4*kk + g) ^ (ln & 7)) << 3)];
        acc[j] = MFMA16(bv, af[kk], acc[j]);
      }
    // packed store: lane holds 4 consecutive n (d) for its row
    #pragma unroll
    for(int j=0;j<4;j++){
      int nb = c*64 + j*16 + g*4;        // 16-aligned frag: never crosses d/RV boundary
      u16* dst; int cc;
      if (nb < 192){ dst = R; cc = nb; } else { dst = V; cc = nb - 192; }
      int h = cc >> 5, d0 = cc & 31;
      bf16x4 pk;
      #pragma unroll
      for(int r=0;r<4;r++) pk[r] = (short)f2bf(acc[j][r]);
      *(bf16x4*)&dst[mbase + (size_t)h*hstride + d0] = pk;
    }
  }
}

// ---------------- K2: per-head, 4-chunk k_attn; phase B hoisted (EN is wave-private) ----------------
__global__ __launch_bounds__(256) void k_attn(
    const u16* __restrict__ r_lat_g, const u16* __restrict__ v_lat_g,
    const u16* __restrict__ r_pat_g, const u16* __restrict__ v_pat_g,
    u16* __restrict__ Opat,            // [B][4096][192] bf16 (pre-projection)
    float* __restrict__ numT_ws,       // [B*H][NSC][64*32]
    float* __restrict__ rowsum_ws){    // [B*H][NSC][64]
  const float SCALE = 0.17677669529663687f;
  const int sc = blockIdx.x, h = blockIdx.y, b = blockIdx.z;
  const int bh = b*H_ + h;
  const int t = threadIdx.x, lane = t&63, w = t>>6, g = lane>>4, ln = lane&15;
  __shared__ u16 RL [64*40];    // r_lat [l][d]
  __shared__ u16 VLT[32*72];    // v_lat^T [d][l]
  __shared__ u16 EN [128*72];   // normalized e [p][l] — WAVE-PRIVATE rows
  __shared__ u16 ET [64*136];   // raw e^T [l][p]
  __shared__ float RS[4*64];
  __shared__ u16 POOL[128*40];  // RP [p][d] pad40 / VPT [d][p] pad136 overlay
  u16* RP  = POOL;
  u16* VPT = POOL;
  const f32x4 ZF = {0.f,0.f,0.f,0.f};

  // stage RL, VLT once per block
  const size_t latbase = (size_t)bh * (NL_*HD_);
  { int row = t>>2, col = (t&3)*8;
    *(bf16x8*)&RL[row*40+col] = *(const bf16x8*)&r_lat_g[latbase + row*32 + col]; }
  { int l = t>>2, dd = (t&3)*8;
    bf16x8 v = *(const bf16x8*)&v_lat_g[latbase + l*32 + dd];
    #pragma unroll
    for(int jj=0;jj<8;jj++) VLT[(dd+jj)*72 + l] = (u16)v[jj]; }

  const int p0 = t>>2, dd0 = (t&3)*8;
  const size_t pb0 = ((size_t)bh*NP_ + (size_t)sc*(CPB_*PC_))*HD_;
  // prologue: load chunk 0 r/v into regs
  bf16x8 rcur0 = *(const bf16x8*)&r_pat_g[pb0 + (size_t)p0*32 + dd0];
  bf16x8 rcur1 = *(const bf16x8*)&r_pat_g[pb0 + (size_t)(64+p0)*32 + dd0];
  bf16x8 vcur0 = *(const bf16x8*)&v_pat_g[pb0 + (size_t)p0*32 + dd0];
  bf16x8 vcur1 = *(const bf16x8*)&v_pat_g[pb0 + (size_t)(64+p0)*32 + dd0];

  f32x4 nmT[2]; nmT[0]=ZF; nmT[1]=ZF;     // row-softmax numerator accum, TRANSPOSED [d][l]
  float rs[4] = {0.f,0.f,0.f,0.f};        // rowsum accum

  for (int c = 0; c < CPB_; ++c){
    // write RP (after prev b4, so VPT reads are done)
    *(bf16x8*)&RP[p0*40 + dd0]      = rcur0;
    *(bf16x8*)&RP[(64+p0)*40 + dd0] = rcur1;
    __syncthreads();   // b1: RP ready (iter0: RL/VLT also)

    // ---- phase A: scores s[p][l], wave's 32 p, all 64 l ----
    f32x4 sf[2][4];
    { bf16x8 a0 = *(const bf16x8*)&RP[(w*32      + ln)*40 + g*8];
      bf16x8 a1 = *(const bf16x8*)&RP[(w*32 + 16 + ln)*40 + g*8];
      #pragma unroll
      for(int j=0;j<4;j++){
        bf16x8 bl = *(const bf16x8*)&RL[(j*16 + ln)*40 + g*8];
        sf[0][j] = MFMA16(a0, bl, ZF);
        sf[1][j] = MFMA16(a1, bl, ZF);
      } }

    // issue next chunk's loads early (hide under B/C phases)
    bf16x8 rnxt0, rnxt1, vnxt0, vnxt1;
    const bool more = (c+1 < CPB_);
    if (more){
      const size_t pbn = pb0 + (size_t)(c+1)*(PC_*HD_);
      rnxt0 = *(const bf16x8*)&r_pat_g[pbn + (size_t)p0*32 + dd0];
      rnxt1 = *(const bf16x8*)&r_pat_g[pbn + (size_t)(64+p0)*32 + dd0];
      vnxt0 = *(const bf16x8*)&v_pat_g[pbn + (size_t)p0*32 + dd0];
      vnxt1 = *(const bf16x8*)&v_pat_g[pbn + (size_t)(64+p0)*32 + dd0];
    }

    float e[2][4][4], rcs[2][4];
    #pragma unroll
    for(int i=0;i<2;i++)
      #pragma unroll
      for(int r=0;r<4;r++){
        float cs = 0.f;
        #pragma unroll
        for(int j=0;j<4;j++){
          float ev = __expf(sf[i][j][r] * SCALE);
          e[i][j][r] = ev; cs += ev; rs[j] += ev;
        }
        cs += __shfl_xor(cs,1); cs += __shfl_xor(cs,2);
        cs += __shfl_xor(cs,4); cs += __shfl_xor(cs,8);
        rcs[i][r] = 1.0f / cs;
      }
    #pragma unroll
    for(int i=0;i<2;i++)
      #pragma unroll
      for(int j=0;j<4;j++){
        #pragma unroll
        for(int r=0;r<4;r++)
          EN[(w*32 + i*16 + g*4 + r)*72 + j*16 + ln] = f2bf(e[i][j][r]*rcs[i][r]);
        bf16x4 pk;
        #pragma unroll
        for(int r=0;r<4;r++) pk[r] = (short)f2bf(e[i][j][r]);
        *(bf16x4*)&ET[(j*16+ln)*136 + w*32 + i*16 + g*4] = pk;
      }

    // ---- phase B (HOISTED, pre-b2): EN rows are wave-private; VLT block-static ----
    f32x4 opT[2][2];   // [jd d-frag][i p-frag]
    #pragma unroll
    for(int jd=0;jd<2;jd++){ opT[jd][0]=ZF; opT[jd][1]=ZF; }
    #pragma unroll
    for(int ks=0; ks<2; ks++){
      bf16x8 bv[2];
      #pragma unroll
      for(int jd=0;jd<2;jd++) bv[jd] = *(const bf16x8*)&VLT[(jd*16+ln)*72 + ks*32 + g*8];
      #pragma unroll
      for(int i=0;i<2;i++){
        bf16x8 afen = *(const bf16x8*)&EN[(w*32 + i*16 + ln)*72 + ks*32 + g*8];
        #pragma unroll
        for(int jd=0;jd<2;jd++) opT[jd][i] = MFMA16(bv[jd], afen, opT[jd][i]);
      }
    }
    const size_t obase = ((size_t)b*NP_ + (size_t)(sc*CPB_ + c)*PC_)*DIM_ + h*32;
    #pragma unroll
    for(int jd=0;jd<2;jd++)
      #pragma unroll
      for(int i=0;i<2;i++){
        int p = w*32 + i*16 + ln, d0 = jd*16 + g*4;
        bf16x4 pk;
        #pragma unroll
        for(int r=0;r<4;r++) pk[r] = (short)f2bf(opT[jd][i][r]);
        *(bf16x4*)&Opat[obase + (size_t)p*DIM_ + d0] = pk;
      }
    __syncthreads();   // b2: ET visible; all RP reads done -> POOL free

    // stage VPT [d][p] from vcur
    #pragma unroll
    for(int jj=0;jj<8;jj++){
      VPT[(dd0+jj)*136 + p0]      = (u16)vcur0[jj];
      VPT[(dd0+jj)*136 + 64 + p0] = (u16)vcur1[jj];
    }
    __syncthreads();   // b3: VPT writes complete

    // ---- phase C: row-softmax numerator, SWAPPED (D[d][l]), accumulate ----
    #pragma unroll
    for(int ks=0; ks<4; ks++){
      bf16x8 afet = *(const bf16x8*)&ET[(w*16+ln)*136 + ks*32 + g*8];
      #pragma unroll
      for(int dj=0;dj<2;dj++){
        bf16x8 bv = *(const bf16x8*)&VPT[(dj*16+ln)*136 + ks*32 + g*8];
        nmT[dj] = MFMA16(bv, afet, nmT[dj]);
      }
    }
    __syncthreads();   // b4: ET/VPT reads done -> next chunk may overwrite

    if (more){ rcur0=rnxt0; rcur1=rnxt1; vcur0=vnxt0; vcur1=vnxt1; }
  }

  // ---- epilogue: rowsum + numT (once per block) ----
  #pragma unroll
  for(int j=0;j<4;j++){
    float vs = rs[j];
    vs += __shfl_xor(vs,16); vs += __shfl_xor(vs,32);
    if (g == 0) RS[w*64 + j*16 + ln] = vs;
  }
  __syncthreads();
  if (t < 64)
    rowsum_ws[((size_t)bh*NSC_ + sc)*64 + t] = RS[t] + RS[64+t] + RS[128+t] + RS[192+t];
  float* dstN = numT_ws + ((size_t)bh*NSC_ + sc)*2048;
  #pragma unroll
  for(int dj=0;dj<2;dj++){
    int l = w*16 + ln, d0 = dj*16 + g*4;
    *(f32x4*)&dstN[l*32 + d0] = nmT[dj];
  }
}

// ---------------- K3a: reduce super-chunk partials -> attn_lat [B][64][192] bf16 ----------------
__global__ __launch_bounds__(256) void k_lat_reduce(const float* __restrict__ numT_ws,
    const float* __restrict__ rowsum_ws, u16* __restrict__ attn_lat){
  int bh = blockIdx.x, b = bh / H_, h = bh - b*H_;
  __shared__ float RSs[64];
  int t = threadIdx.x;
  if (t < 64){
    float s = 0.f;
    for(int c=0;c<NSC_;c++) s += rowsum_ws[((size_t)bh*NSC_ + c)*64 + t];
    RSs[t] = 1.0f / s;
  }
  __syncthreads();
  for(int idx = t; idx < 2048; idx += 256){
    int l = idx >> 5, dd = idx & 31;
    float s = 0.f;
    for(int c=0;c<NSC_;c++) s += numT_ws[((size_t)bh*NSC_ + c)*2048 + idx];
    attn_lat[((size_t)b*NL_ + l)*DIM_ + h*32 + dd] = f2bf(s * RSs[l]);
  }
}

// ---------------- K3b: out_lat = attn_lat @ W_proj_lat + b (f32 out) ----------------
__global__ __launch_bounds__(256) void k_proj_lat(const u16* __restrict__ A,
    const u16* __restrict__ Wt, const float* __restrict__ bias, float* __restrict__ out){
  int b = blockIdx.x;
  __shared__ u16 As[64*40];
  __shared__ u16 Bs[192*40];
  int t = threadIdx.x, lane = t&63, w = t>>6, g = lane>>4, ln = lane&15;
  const f32x4 ZF = {0.f,0.f,0.f,0.f};
  f32x4 acc[4][3];
  #pragma unroll
  for(int i=0;i<4;i++)
    #pragma unroll
    for(int j=0;j<3;j++) acc[i][j]=ZF;
  for(int k0=0;k0<192;k0+=32){
    bf16x8 av; bf16x8 bv[3];
    { int row = t>>2, col=(t&3)*8;
      av = *(const bf16x8*)&A[((size_t)b*NL_ + row)*DIM_ + k0 + col]; }
    #pragma unroll
    for(int it=0;it<3;it++){
      int e = it*2048 + t*8, row = e>>5, col = (t&3)*8;
      bv[it] = *(const bf16x8*)&Wt[(size_t)row*192 + k0 + col];
    }
    if (k0) __syncthreads();
    { int row = t>>2, col=(t&3)*8; *(bf16x8*)&As[row*40+col] = av; }
    #pragma unroll
    for(int it=0;it<3;it++){
      int e = it*2048 + t*8, row = e>>5, col = (t&3)*8;
      *(bf16x8*)&Bs[row*40+col] = bv[it];
    }
    __syncthreads();
    bf16x8 bw[3];
    #pragma unroll
    for(int jf=0;jf<3;jf++) bw[jf] = *(const bf16x8*)&Bs[(w*48 + jf*16 + ln)*40 + g*8];
    #pragma unroll
    for(int lf=0;lf<4;lf++){
      bf16x8 af = *(const bf16x8*)&As[(lf*16 + ln)*40 + g*8];
      #pragma unroll
      for(int jf=0;jf<3;jf++) acc[lf][jf] = MFMA16(af, bw[jf], acc[lf][jf]);
    }
  }
  #pragma unroll
  for(int lf=0;lf<4;lf++)
    #pragma unroll
    for(int jf=0;jf<3;jf++){
      int j = w*48 + jf*16 + ln;
      float bs = bias[j];
      #pragma unroll
      for(int r=0;r<4;r++){
        int l = lf*16 + g*4 + r;
        out[((size_t)b*NL_ + l)*DIM_ + j] = acc[lf][jf][r] + bs;
      }
    }
}

// ---------------- K4: out_pat = Opat @ W_proj_pat + b (f32 out) ----------------
// r15 structure + T2 XOR-swizzled Bs (stride 192); float4 stores.
__global__ __launch_bounds__(256,8) void k_proj_pat(const u16* __restrict__ X,
    const u16* __restrict__ Wt, const float* __restrict__ bias, float* __restrict__ out){
  __shared__ u16 Bs[64*192];
  const int t = threadIdx.x;
  const int m0 = blockIdx.x*64;
  const int lane = t & 63, w = t >> 6, g = lane >> 4, ln = lane & 15;
  const int srB = t >> 2, bq = t & 3;
  const f32x4 ZF = {0.f,0.f,0.f,0.f};

  // A fragments in regs (bf16 input, direct loads): wave's 16 rows
  bf16x8 af[6];
  #pragma unroll
  for (int kk=0;kk<6;kk++)
    af[kk] = *(const bf16x8*)&X[(size_t)(m0 + w*16 + ln)*192 + kk*32 + g*8];

  const int mrow = m0 + w*16 + ln;

  for (int c = 0; c < 3; ++c){
    if (c) __syncthreads();
    #pragma unroll
    for (int it=0; it<6; it++){
      int sl = (6*bq + it) ^ (srB & 7);
      *(bf16x8*)&Bs[srB*192 + sl*8] =
        *(const bf16x8*)&Wt[(size_t)(c*64 + srB)*192 + bq*48 + it*8];
    }
    __syncthreads();

    f32x4 acc[4];
    #pragma unroll
    for(int j=0;j<4;j++) acc[j]=ZF;
    #pragma unroll
    for (int kk=0; kk<6; kk++)
      #pragma unroll
      for (int j=0; j<4; j++){
        bf16x8 bv = *(const bf16x8*)&Bs[(j*16 + ln)*192 + (((4*kk + g) ^ (ln & 7)) << 3)];
        acc[j] = MFMA16(bv, af[kk], acc[j]);
      }
    #pragma unroll
    for(int j=0;j<4;j++){
      int nb = c*64 + j*16 + g*4;
      float4 bs4 = *(const float4*)&bias[nb];
      float4 o;
      o.x = acc[j][0] + bs4.x;
      o.y = acc[j][1] + bs4.y;
      o.z = acc[j][2] + bs4.z;
      o.w = acc[j][3] + bs4.w;
      *(float4*)&out[(size_t)mrow*192 + nb] = o;
    }
  }
}

// ---------------- launch ----------------
extern "C" void kernel_launch(void* const* d_in, const int* in_sizes, int n_in,
                              void* d_out, int out_size, void* d_ws, size_t ws_size,
                              hipStream_t stream){
  const float* x_lat  = (const float*)d_in[0];
  const float* x_pat  = (const float*)d_in[1];
  const float* W_rv_l = (const float*)d_in[2];
  const float* W_rv_p = (const float*)d_in[3];
  const float* W_pj_l = (const float*)d_in[4];
  const float* b_pj_l = (const float*)d_in[5];
  const float* W_pj_p = (const float*)d_in[6];
  const float* b_pj_p = (const float*)d_in[7];
  float* out = (float*)d_out;

  char* ws = (char*)d_ws;
  size_t off = 0;
  auto alloc = [&](size_t bytes)->void*{ void* p = ws + off; off += (bytes + 255) & ~(size_t)255; return p; };
  u16* WtRL   = (u16*)alloc((size_t)384*192*2);
  u16* WtRP   = (u16*)alloc((size_t)384*192*2);
  u16* WtPL   = (u16*)alloc((size_t)192*192*2);
  u16* WtPP   = (u16*)alloc((size_t)192*192*2);
  u16* r_lat  = (u16*)alloc((size_t)B_*H_*NL_*HD_*2);
  u16* v_lat  = (u16*)alloc((size_t)B_*H_*NL_*HD_*2);
  u16* r_pat  = (u16*)alloc((size_t)B_*H_*NP_*HD_*2);
  u16* v_pat  = (u16*)alloc((size_t)B_*H_*NP_*HD_*2);
  u16* Opat   = (u16*)alloc((size_t)B_*NP_*DIM_*2);
  float* numT = (float*)alloc((size_t)B_*H_*NSC_*64*32*4);
  float* rsum = (float*)alloc((size_t)B_*H_*NSC_*64*4);
  u16* attn_l = (u16*)alloc((size_t)B_*NL_*DIM_*2);

  k0_transpose<<<64,256,0,stream>>>(W_rv_l, W_rv_p, W_pj_l, W_pj_p, WtRL, WtRP, WtPL, WtPP);
  k_rv<<<dim3((B_*NP_)/64),256,0,stream>>>(x_pat, WtRP, r_pat, v_pat, NP_, 12);
  k_rv<<<dim3((B_*NL_)/64),256,0,stream>>>(x_lat, WtRL, r_lat, v_lat, NL_, 6);
  k_attn<<<dim3(NSC_, H_, B_),256,0,stream>>>(r_lat, v_lat, r_pat, v_pat, Opat, numT, rsum);
  k_lat_reduce<<<B_*H_,256,0,stream>>>(numT, rsum, attn_l);
  k_proj_lat<<<B_,256,0,stream>>>(attn_l, WtPL, b_pj_l, out);
  k_proj_pat<<<dim3((B_*NP_)/64),256,0,stream>>>(Opat, WtPP, b_pj_p, out + (size_t)B_*NL_*DIM_);
}